// Round 9
// baseline (269.205 us; speedup 1.0000x reference)
//
#include <hip/hip_runtime.h>
#include <cmath>

// ---------------------------------------------------------------------------
// EquivariantCorrectionHead — round 20: fold stage-2 matmuls into S2 MFMAs.
// Round-8 post-mortem: 2-barrier skeleton is right, but computing a=V110@h2
// as per-lane dot2 chains cost ~96 dot2 + ~160 LDS reads/lane (VALUBusy 38->43,
// dur 113->128). Fix by linearity: h2 = Cvv.t + p5 with Cvv = wc@s, p5 = W111@q
//   a  = V110@h2 = (V110.wc)@s . t + (V110.W111)@q   == same structure as h2!
//   g  = Mr@h0   = (Mr.W0)@[ss|tt]                   == h0 eliminated.
// Setup pre-multiplies wc2=V110.wc, W111b=V110.W111, Mg=Mr.W0 (fp32, rounded
// once to fp16). S2 runs 88 MFMAs over 8 waves (was 50 — MFMA pipe is ~2%
// utilized, free); S3 is ~50 dot2 + ~40 LDS reads, no h2 LDS round-trip.
//  S1  marshal + next-group register prefetch
//  B1
//  S2  MFMA: g (w0, FMg LDS), Cvv (w1-2, FWC streamed from L2),
//      Cvv2 (w3-4, FWC2 streamed), p5/p52 (w5-7, FW111/FW111b LDS)
//  B2
//  S3  h2r = Cvv.t + p5; a5 = Cvv2.t + p52; g read; CG + reduce + store.
// 2 barriers/iter; cross-iteration safety as round 19 (S1 writes scr only
// after B2; S2 writes outputs only after B1).
// Residency model (r12-r19 calibrated): VGPR granule 64; <=128 regs + LDS
// <=80KB -> 2 blocks/CU; grid MUST be 512 (768 = 1.37x straggler tail, r16).
// LDS 79.95KB. Plain launch_bounds(512) — natural VGPR, zero spill.
// ---------------------------------------------------------------------------

#define DEVINL static __device__ __forceinline__

typedef _Float16 half2_t __attribute__((ext_vector_type(2)));
typedef _Float16 half8_t __attribute__((ext_vector_type(8)));
typedef float    f32x4_t __attribute__((ext_vector_type(4)));
union H8 { half8_t v; half2_t p[4]; };

// ---- g_wsh offsets in HALVES ----
#define GFWC    0      // 18 x 256: wc frags (streamed from L2 in S2)
#define GFWC2   4608   // 18 x 256: V110-folded wc frags (streamed)
#define GSTGG   9216   // start of LDS-staged region:
#define GFMG    9216   //   12 x 512: Mg = Mr.W0 frags (2 Mt x 6 Ks, K=192)
#define GFW111  15360  //   4 x 512:  W111 frags (2 Mt x 2 Ks, p>=45 zero)
#define GF111B  17408  //   4 x 512:  V110-folded W111 frags
#define GWSHH   19456

// ---- slabh (LDS) offsets in HALVES ----
#define SFMG    0
#define SFW111  6144
#define SF111B  8192
#define SLABH   10240  // 20480 B

__device__ __align__(16) _Float16 g_wsh[GWSHH];

struct CPack { float v[32]; };

// C222 nonzero superset (exact O(3) parity selection rule)
static constexpr int CIa[32] = {2,2,2,4,2,4,4,4, 2,0,0, 2,1,1, 2,3,3, 4,0,0, 4,1,1, 4,3,3, 0,0,1,1,3,3};
static constexpr int CJa[32] = {2,2,4,2,4,2,4,4, 0,2,0, 1,2,1, 3,2,3, 0,4,0, 1,4,1, 3,4,3, 1,3,0,3,0,1};
static constexpr int CKa[32] = {2,4,2,2,4,4,2,4, 0,0,2, 1,1,2, 3,3,2, 0,0,4, 1,1,4, 3,3,4, 3,1,3,0,1,0};

__host__ __device__ inline void tri_uv(int p, int n, int& u, int& v) {
  int base = 0;
  for (int x = 0; x < n; x++) {
    int c = n - x;
    if (p < base + c) { u = x; v = x + (p - base); return; }
    base += c;
  }
  u = n - 1; v = n - 1;
}

// ---- host analytic C222 (round-4 proven sign) ----
static double h_trE3(const double A[3][3], const double B[3][3], const double C[3][3]) {
  double t = 0.0;
  for (int r = 0; r < 3; r++)
    for (int c = 0; c < 3; c++) {
      double ab = 0.0;
      for (int m = 0; m < 3; m++) ab += A[r][m] * B[m][c];
      t += ab * C[c][r];
    }
  return t;
}
static void computeC(CPack& out) {
  const double s2i = 0.7071067811865475244, s6i = 0.4082482904638630164;
  double E[5][3][3] = {
    {{0, s2i, 0}, {s2i, 0, 0}, {0, 0, 0}},
    {{0, 0, 0}, {0, 0, s2i}, {0, s2i, 0}},
    {{-s6i, 0, 0}, {0, -s6i, 0}, {0, 0, 2.0 * s6i}},
    {{0, 0, s2i}, {0, 0, 0}, {s2i, 0, 0}},
    {{s2i, 0, 0}, {0, -s2i, 0}, {0, 0, 0}}
  };
  double T[125], nrm = 0.0;
  for (int f = 0; f < 125; f++) {
    int i = f / 25, j = (f / 5) % 5, k = f % 5;
    T[f] = h_trE3(E[i], E[j], E[k]) + h_trE3(E[i], E[k], E[j]);
    nrm += T[f] * T[f];
  }
  nrm = std::sqrt(nrm);
  int am = 0; double mx = std::fabs(T[0]);
  for (int q = 1; q < 125; q++) { double v = std::fabs(T[q]); if (v > mx) { mx = v; am = q; } }
  const double scale = ((T[am] < 0.0) ? 1.0 : -1.0) / nrm;
  for (int s = 0; s < 32; s++)
    out.v[s] = (float)(scale * T[(CIa[s] * 5 + CJa[s]) * 5 + CKa[s]]);
}

// ---- device helpers ----
DEVINL float dot2f(half2_t a, half2_t b, float c) {
#if __has_builtin(__builtin_amdgcn_fdot2)
  return __builtin_amdgcn_fdot2(a, b, c, false);
#else
  return fmaf((float)a[0], (float)b[0], fmaf((float)a[1], (float)b[1], c));
#endif
}
DEVINL half2_t pk2(float a, float b) {
  auto r = __builtin_amdgcn_cvt_pkrtz(a, b);
  half2_t o;
  __builtin_memcpy(&o, &r, sizeof(o));
  return o;
}
DEVINL int h2i(half2_t h) { int i; __builtin_memcpy(&i, &h, 4); return i; }
DEVINL half2_t i2h(int i) { half2_t h; __builtin_memcpy(&h, &i, 4); return h; }
DEVINL f32x4_t mfma16(half8_t a, half8_t b, f32x4_t c) {
  return __builtin_amdgcn_mfma_f32_16x16x32_f16(a, b, c, 0, 0, 0);
}
DEVINL void store4h(_Float16* p, f32x4_t d) {
  int2 v;
  v.x = h2i(pk2(d[0], d[1]));
  v.y = h2i(pk2(d[2], d[3]));
  *(int2*)p = v;
}

// In-loop barrier: drain LDS (lgkmcnt) for cross-wave visibility, but do NOT
// drain vmcnt — cross-iteration global prefetches must stay in flight.
DEVINL void bar_lds() {
  asm volatile("s_waitcnt lgkmcnt(0)" ::: "memory");
  __builtin_amdgcn_s_barrier();
  __builtin_amdgcn_sched_barrier(0);
}

// ---------------------------------------------------------------------------
// Setup: pack weights as MFMA A-fragments, including V110/Mr-FOLDED variants
// (fp32 accumulation, single fp16 rounding). Constants folded.
// ---------------------------------------------------------------------------
__global__ void ech_setup(const float* __restrict__ w000, const float* __restrict__ w110,
                          const float* __restrict__ w011, const float* __restrict__ w101,
                          const float* __restrict__ w111, const float* __restrict__ v010,
                          const float* __restrict__ v100, const float* __restrict__ v110) {
  const float c0   = 1.0f / sqrtf(337.0f);
  const float inv5 = 0.44721359549995794f;
  const float c2   = sqrtf(5.0f / 369.0f);
  const float dm   = sqrtf(5.0f / 3072.0f) * inv5;
  int gid = blockIdx.x * blockDim.x + threadIdx.x;
  int gs  = gridDim.x * blockDim.x;

  // GFWC: wc[m=w*9+v][k=u] frags, quads 0-1 only (K=16)
  for (int idx = gid; idx < 4608; idx += gs) {
    int j = idx & 7, L = (idx >> 3) & 31, t = idx >> 8;
    int m = t * 16 + (L & 15);
    int w = m / 9, v = m % 9;
    int u = (L >> 4) * 8 + j;
    g_wsh[GFWC + idx] =
        (_Float16)(c2 * inv5 * (w011[(u * 9 + v) * 32 + w] + w101[(v * 16 + u) * 32 + w]));
  }
  // GFWC2: wc2[m=u'*9+v][k=u] = sum_w V110[u'][w] * wc[w*9+v][u]
  for (int idx = gid; idx < 4608; idx += gs) {
    int j = idx & 7, L = (idx >> 3) & 31, t = idx >> 8;
    int m = t * 16 + (L & 15);
    int up = m / 9, v = m % 9;
    int u = (L >> 4) * 8 + j;
    float acc = 0.f;
    for (int w = 0; w < 32; w++)
      acc += v110[up * 32 + w] * (w011[(u * 9 + v) * 32 + w] + w101[(v * 16 + u) * 32 + w]);
    g_wsh[GFWC2 + idx] = (_Float16)(c2 * inv5 * acc);
  }
  // GFMG: Mg[w'][p] = sum_w Mr[w'][w] * W0c[w][p]  (g = Mg @ [ss|tt])
  //   Mr[w'][w] = dm*(v010[w][w'] + v100[w'][w]);  W0c = c0*sym(w000)|c0*inv5*sym(w110)
  for (int idx = gid; idx < 6144; idx += gs) {
    int j = idx & 7, L = (idx >> 3) & 63, tk = idx >> 9;
    int mt = tk / 6, ks = tk % 6;
    int wp = mt * 16 + (L & 15);
    int p = ks * 32 + (L >> 4) * 8 + j;
    float acc = 0.f;
    if (p < 136) {
      int pu, pv; tri_uv(p, 16, pu, pv);
      for (int w = 0; w < 32; w++) {
        float w0c = w000[(pu * 16 + pv) * 32 + w] + (pu != pv ? w000[(pv * 16 + pu) * 32 + w] : 0.f);
        acc += (v010[w * 32 + wp] + v100[wp * 32 + w]) * w0c;
      }
      acc *= c0 * dm;
    } else if (p < 181) {
      int pu, pv; tri_uv(p - 136, 9, pu, pv);
      for (int w = 0; w < 32; w++) {
        float w1 = w110[(pu * 9 + pv) * 32 + w] + (pu != pv ? w110[(pv * 9 + pu) * 32 + w] : 0.f);
        acc += (v010[w * 32 + wp] + v100[wp * 32 + w]) * w1;
      }
      acc *= c0 * inv5 * dm;
    }
    g_wsh[GFMG + idx] = (_Float16)acc;
  }
  // GFW111: W111c[m=w][k=p] frags (p>=45 zero)
  for (int idx = gid; idx < 2048; idx += gs) {
    int j = idx & 7, L = (idx >> 3) & 63, t = idx >> 9;
    int mt = t >> 1, ks = t & 1;
    int w = mt * 16 + (L & 15);
    int p = ks * 32 + (L >> 4) * 8 + j;
    float x = 0.0f;
    if (p < 45) { int u, v; tri_uv(p, 9, u, v);
      x = c2 * (w111[(u * 9 + v) * 32 + w] + (u != v ? w111[(v * 9 + u) * 32 + w] : 0.0f)); }
    g_wsh[GFW111 + idx] = (_Float16)x;
  }
  // GF111B: W111b[m=u'][p] = sum_w V110[u'][w] * W111c[w][p]
  for (int idx = gid; idx < 2048; idx += gs) {
    int j = idx & 7, L = (idx >> 3) & 63, t = idx >> 9;
    int mt = t >> 1, ks = t & 1;
    int wp = mt * 16 + (L & 15);
    int p = ks * 32 + (L >> 4) * 8 + j;
    float acc = 0.f;
    if (p < 45) {
      int pu, pv; tri_uv(p, 9, pu, pv);
      for (int w = 0; w < 32; w++)
        acc += v110[wp * 32 + w] *
               (w111[(pu * 9 + pv) * 32 + w] + (pu != pv ? w111[(pv * 9 + pu) * 32 + w] : 0.f));
      acc *= c2;
    }
    g_wsh[GF111B + idx] = (_Float16)acc;
  }
}

// ---------------------------------------------------------------------------
// Main fused kernel
// ---------------------------------------------------------------------------
#define ESZ 444          // per-element scratch words (half-stride 888)
#define P5MT 272         // p5/p52 mt-stride (halves)
#define P5K  544         // p5/p52 k-stride
__global__ void __launch_bounds__(512)
ech_main(const float* __restrict__ sc, const float* __restrict__ t2s,
         float* __restrict__ out, int nGroups, CPack C) {
  __shared__ __align__(16) _Float16 slabh[SLABH];       // 20480 B
  __shared__ __align__(16) float scr[16 * ESZ];         // 28416 B
  __shared__ __align__(16) _Float16 unionH[5440];       // p5(2720) + p52(2720)
  __shared__ __align__(16) _Float16 cvvH[16 * 288];     // 9216 B
  __shared__ __align__(16) _Float16 cvv2H[16 * 288];    // 9216 B
  __shared__ __align__(16) _Float16 gst[16 * 40];       // 1280 B
  __shared__ int pairs9[48];
  __shared__ int sspair[68];
  // total 79952 B -> 2 blocks/CU

  const int tid  = threadIdx.x;
  const int lane = tid & 31;
  const int sub  = tid >> 5;
  const int w    = lane;

  _Float16* p5H  = unionH;           // [k][mt][e][16]
  _Float16* p52H = unionH + 2720;    // [k][mt][e][16]

  for (int i = tid; i < SLABH / 8; i += 512)
    ((float4*)slabh)[i] = ((const float4*)(g_wsh + GSTGG))[i];
  if (tid < 45) { int u, v; tri_uv(tid, 9, u, v); pairs9[tid] = u | (v << 4); }
  if (tid < 68) {
    int u0, v0, u1, v1;
    tri_uv(2 * tid, 16, u0, v0);
    tri_uv(2 * tid + 1, 16, u1, v1);
    sspair[tid] = u0 | (v0 << 4) | (u1 << 8) | (v1 << 12);
  }

  constexpr int L2R[8] = {0, 1, 2, 4, 24, 26, 35, 38};

  // per-element scratch (words):
  float*     E    = scr + sub * ESZ;
  float*     Araw = E;                          // 0..199 (qBe overlays 0..159)
  _Float16*  qBe  = (_Float16*)E;               // [k<5][64] halves
  float*     tb   = E + 200;                    // [9][8] f32
  _Float16*  sshh = (_Float16*)(E + 272);       // 136 h
  _Float16*  tthh = (_Float16*)(E + 340);       // 56 h (45 used + 11 pad)
  _Float16*  thh  = (_Float16*)(E + 368);       // [5][16] h
  float*     sL   = E + 408;                    // 16 f32
  int*       spad = (int*)(E + 424);            // 16 ints (32 halves)

  // one-time pad zeroing (regions never clobbered by staging)
  if (lane < 11)      tthh[45 + lane] = (_Float16)0.f;
  else if (lane < 16) thh[(lane - 11) * 16 + 9] = (_Float16)0.f;
  if (lane >= 24)     spad[lane - 16] = 0;

  // ---- prologue prefetch for first group ----
  float4 pf0 = {0.f, 0.f, 0.f, 0.f};
  float4 pf1 = {0.f, 0.f, 0.f, 0.f};
  float4 pfs = {0.f, 0.f, 0.f, 0.f};
  if (blockIdx.x < nGroups) {
    const int b0 = blockIdx.x * 16 + sub;
    const float4* src = (const float4*)(t2s + (size_t)b0 * 200);
    pf0 = src[lane];
    if (lane < 18) pf1 = src[lane + 32];
    if (lane < 4)  pfs = ((const float4*)(sc + (size_t)b0 * 16))[lane];
  }
  __syncthreads();

  for (int grp = blockIdx.x; grp < nGroups; grp += gridDim.x) {
    const int b = grp * 16 + sub;

    // ======== S1: per-element marshaling (from prefetched regs) ========
    {
      float4* Av = (float4*)Araw;
      Av[lane] = pf0;
      if (lane < 18) Av[lane + 32] = pf1;
      if (lane < 4) ((float4*)sL)[lane] = pfs;
    }
    // issue NEXT group's loads — stay in flight across the in-loop barriers.
    {
      const int gnext = grp + gridDim.x;
      if (gnext < nGroups) {
        const int bn = gnext * 16 + sub;
        const float4* srcn = (const float4*)(t2s + (size_t)bn * 200);
        pf0 = srcn[lane];
        if (lane < 18) pf1 = srcn[lane + 32];
        if (lane < 4)  pfs = ((const float4*)(sc + (size_t)bn * 16))[lane];
      }
    }
    if (lane < 8) spad[lane] = h2i(pk2(sL[2 * lane], sL[2 * lane + 1]));

    // phase 1: t rows
    #pragma unroll
    for (int it = 0; it < 2; it++) {
      int idx = lane + 32 * it;
      if (idx < 40) {
        int r = idx / 5, c = idx % 5;
        float val = Araw[L2R[r] * 5 + c];
        tb[r * 8 + c] = val;
        thh[c * 16 + r] = (_Float16)val;
      }
    }
    { // kernel-sum row
      int l25 = lane % 25;
      int c2 = l25 / 5, j2 = l25 % 5;
      float acc = 0.f;
      #pragma unroll
      for (int rr = 0; rr < 8; rr++) acc += Araw[(j2 + 5 * rr) * 5 + c2];
      float tot = __shfl(acc, 5 * c2 + 0, 32) + __shfl(acc, 5 * c2 + 1, 32)
                + __shfl(acc, 5 * c2 + 2, 32) + __shfl(acc, 5 * c2 + 3, 32)
                + __shfl(acc, 5 * c2 + 4, 32);
      if (lane < 25 && j2 == 0) { tb[64 + c2] = tot; thh[c2 * 16 + 8] = (_Float16)tot; }
    }

    // phase 2: pairs -> tt + qB (overlays Araw; pads re-zeroed here)
    #pragma unroll
    for (int it = 0; it < 2; it++) {
      int idx = lane + 32 * it;
      if (idx < 45) {
        int pr = pairs9[idx];
        int pu = pr & 15, pv = pr >> 4;
        float4 u4 = *(const float4*)(tb + pu * 8); float u5 = tb[pu * 8 + 4];
        float4 v4 = *(const float4*)(tb + pv * 8); float v5 = tb[pv * 8 + 4];
        float tu[5] = {u4.x, u4.y, u4.z, u4.w, u5};
        float tv[5] = {v4.x, v4.y, v4.z, v4.w, v5};
        float tt = tu[0]*tv[0] + tu[1]*tv[1] + tu[2]*tv[2] + tu[3]*tv[3] + tu[4]*tv[4];
        tthh[idx] = (_Float16)tt;
        float qk[5] = {0, 0, 0, 0, 0};
        #pragma unroll
        for (int s = 0; s < 32; s++)
          qk[CKa[s]] = fmaf(C.v[s], tu[CIa[s]] * tv[CJa[s]], qk[CKa[s]]);
        #pragma unroll
        for (int k = 0; k < 5; k++) qBe[k * 64 + idx] = (_Float16)qk[k];
      } else {
        #pragma unroll
        for (int k = 0; k < 5; k++) qBe[k * 64 + idx] = (_Float16)0.f;
      }
    }

    // phase 3a: ss pair products
    #pragma unroll
    for (int ii = 0; ii < 3; ii++) {
      int slot = lane + 32 * ii;
      if (slot < 68) {
        int t = sspair[slot];
        int u0 = t & 15, v0 = (t >> 4) & 15, u1 = (t >> 8) & 15, v1 = (t >> 12) & 15;
        *(half2_t*)(sshh + 2 * slot) = pk2(sL[u0] * sL[v0], sL[u1] * sL[v1]);
      }
    }
    bar_lds();   // B1 (also cross-iteration fence for S2-written buffers)

    // ======== S2: MFMA stage (88 MFMAs over 8 waves) ========
    {
      const int wid = tid >> 6;
      const int L   = tid & 63;
      const int e2  = L & 15;
      const int q2  = L >> 4;
      const _Float16* scrH = (const _Float16*)scr;
      if (wid == 0) {
        // g = Mg @ [ss|tt]  (FMg in LDS — shortest-latency path for the
        // longest serial chain)
        f32x4_t a0 = {0.f, 0.f, 0.f, 0.f}, a1 = {0.f, 0.f, 0.f, 0.f};
        const _Float16* fw  = slabh + SFMG + L * 8;
        const _Float16* ssb = scrH + e2 * (2 * ESZ) + 544;
        #pragma unroll
        for (int ks = 0; ks < 6; ks++) {
          half8_t bb = *(const half8_t*)(ssb + ks * 32 + q2 * 8);
          a0 = mfma16(*(const half8_t*)(fw + ks * 512), bb, a0);
          a1 = mfma16(*(const half8_t*)(fw + (6 + ks) * 512), bb, a1);
        }
        store4h(gst + e2 * 40 + q2 * 4, a0);
        store4h(gst + e2 * 40 + 16 + q2 * 4, a1);
      } else if (wid <= 4) {
        // Cvv (w1-2, GFWC) / Cvv2 (w3-4, GFWC2) — A-frags streamed from L2
        // (9 independent MFMA+store units per wave hide the load latency)
        const _Float16* spb = scrH + e2 * (2 * ESZ) + 848;
        half8_t bb = *(const half8_t*)(spb + q2 * 8);
        const int t0 = ((wid - 1) & 1) * 9;
        const _Float16* gw = g_wsh + ((wid <= 2) ? GFWC : GFWC2);
        _Float16* dst = (wid <= 2) ? cvvH : cvv2H;
        half8_t wz = {0, 0, 0, 0, 0, 0, 0, 0};
        #pragma unroll
        for (int t = 0; t < 9; t++) {
          half8_t wa = (q2 < 2)
              ? *(const half8_t*)(gw + (t0 + t) * 256 + (size_t)L * 8) : wz;
          f32x4_t z4 = {0.f, 0.f, 0.f, 0.f};
          f32x4_t d = mfma16(wa, bb, z4);
          store4h(dst + e2 * 288 + (t0 + t) * 16 + q2 * 4, d);
        }
      } else {
        // p5 (units 0-4, FW111) and p52 (units 5-9, FW111b), both LDS.
        // w5:{0,1,2}  w6:{3,4,5}  w7:{6,7,8,9}
        const int base = (wid - 5) * 3;
        const int cnt  = (wid == 7) ? 4 : 3;
        #pragma unroll
        for (int t = 0; t < 4; t++) {
          if (t < cnt) {
            const int un = base + t;
            const int k  = (un < 5) ? un : un - 5;
            const _Float16* fw = slabh + ((un < 5) ? SFW111 : SF111B) + L * 8;
            _Float16* dst = (un < 5) ? p5H : p52H;
            const _Float16* qb = scrH + e2 * (2 * ESZ) + k * 64;
            f32x4_t d0 = {0.f, 0.f, 0.f, 0.f}, d1 = {0.f, 0.f, 0.f, 0.f};
            #pragma unroll
            for (int ks = 0; ks < 2; ks++) {
              half8_t bb = *(const half8_t*)(qb + ks * 32 + q2 * 8);
              d0 = mfma16(*(const half8_t*)(fw + ks * 512), bb, d0);
              d1 = mfma16(*(const half8_t*)(fw + (2 + ks) * 512), bb, d1);
            }
            store4h(dst + k * P5K + e2 * 16 + q2 * 4, d0);
            store4h(dst + k * P5K + P5MT + e2 * 16 + q2 * 4, d1);
          }
        }
      }
    }
    bar_lds();   // B2

    // ======== S3: per-lane finish (no LDS writes, no further barriers) ====
    float Cvv[9], Cw2[9];
    #pragma unroll
    for (int v = 0; v < 9; v++) {
      Cvv[v] = (float)cvvH[sub * 288 + w * 9 + v];
      Cw2[v] = (float)cvv2H[sub * 288 + w * 9 + v];
    }
    half2_t cpk[5] = { pk2(Cvv[0], Cvv[1]), pk2(Cvv[2], Cvv[3]),
                       pk2(Cvv[4], Cvv[5]), pk2(Cvv[6], Cvv[7]), pk2(Cvv[8], 0.f) };
    half2_t epk[5] = { pk2(Cw2[0], Cw2[1]), pk2(Cw2[2], Cw2[3]),
                       pk2(Cw2[4], Cw2[5]), pk2(Cw2[6], Cw2[7]), pk2(Cw2[8], 0.f) };
    float h2r[5], a5[5];
    const int pidx = (w >> 4) * P5MT + sub * 16 + (w & 15);
    #pragma unroll
    for (int k = 0; k < 5; k++) {
      H8 d; d.v = *(const half8_t*)(thh + k * 16);
      half2_t d4 = *(const half2_t*)(thh + k * 16 + 8);
      float acc = dot2f(cpk[0], d.p[0], 0.f);
      acc = dot2f(cpk[1], d.p[1], acc);
      acc = dot2f(cpk[2], d.p[2], acc);
      acc = dot2f(cpk[3], d.p[3], acc);
      acc = dot2f(cpk[4], d4, acc);
      h2r[k] = acc + (float)p5H[k * P5K + pidx];
      float ac2 = dot2f(epk[0], d.p[0], 0.f);
      ac2 = dot2f(epk[1], d.p[1], ac2);
      ac2 = dot2f(epk[2], d.p[2], ac2);
      ac2 = dot2f(epk[3], d.p[3], ac2);
      ac2 = dot2f(epk[4], d4, ac2);
      a5[k] = ac2 + (float)p52H[k * P5K + pidx];
    }
    float g = (float)gst[sub * 40 + w];

    float yv[5] = {0, 0, 0, 0, 0};
    #pragma unroll
    for (int s = 0; s < 32; s++)
      yv[CKa[s]] = fmaf(C.v[s], h2r[CIa[s]] * a5[CJa[s]], yv[CKa[s]]);

    const float DCONST = sqrtf(5.0f / 3072.0f);
    float z[5];
    #pragma unroll
    for (int k = 0; k < 5; k++) z[k] = fmaf(DCONST, yv[k], g * h2r[k]);

    half2_t z01 = pk2(z[0], z[1]);
    half2_t z23 = pk2(z[2], z[3]);
    float   z4r = z[4];
    #pragma unroll
    for (int st = 1; st <= 16; st <<= 1) {
      z01 = z01 + i2h(__shfl_xor(h2i(z01), st));
      z23 = z23 + i2h(__shfl_xor(h2i(z23), st));
      z4r += __shfl_xor(z4r, st);
    }
    if (lane < 5) {
      float val = (lane == 0) ? (float)z01[0]
                : (lane == 1) ? (float)z01[1]
                : (lane == 2) ? (float)z23[0]
                : (lane == 3) ? (float)z23[1] : z4r;
      out[(size_t)b * 5 + lane] = val;
    }
  }
}

// ---------------------------------------------------------------------------
extern "C" void kernel_launch(void* const* d_in, const int* in_sizes, int n_in,
                              void* d_out, int out_size, void* d_ws, size_t ws_size,
                              hipStream_t stream) {
  (void)n_in; (void)out_size; (void)d_ws; (void)ws_size;

  CPack C;
  computeC(C);

  ech_setup<<<64, 256, 0, stream>>>(
      (const float*)d_in[2], (const float*)d_in[3], (const float*)d_in[4],
      (const float*)d_in[5], (const float*)d_in[6], (const float*)d_in[7],
      (const float*)d_in[8], (const float*)d_in[9]);

  const int B = in_sizes[0] / 16;
  const int nGroups = B / 16;

  // grid MUST equal 2 blocks/CU x 256 CUs = 512: larger grids at 2-block
  // residency create a straggler tail (r16: grid 768 -> 1.37x slower).
  int grid = 512;
  if (grid > nGroups) grid = nGroups;

  ech_main<<<grid, 512, 0, stream>>>(
      (const float*)d_in[0], (const float*)d_in[1], (float*)d_out, nGroups, C);
}